// Round 5
// baseline (461.587 us; speedup 1.0000x reference)
//
#include <hip/hip_runtime.h>

#define TDIM 256
#define BM 64
#define BK 32
#define LDST 40   // LDS row stride in bf16 elements (80 B: 16B-aligned, 2-way-max bank aliasing)
#define NSTEP 8

typedef __attribute__((ext_vector_type(4))) float f32x4;
typedef __attribute__((ext_vector_type(8))) short s16x8;
typedef __attribute__((ext_vector_type(8))) __bf16 bf16x8;

// Native __bf16 casts: compiler lowers f32->bf16 pairs to v_cvt_pk_bf16_f32.
__device__ __forceinline__ s16x8 cvt8(f32x4 v0, f32x4 v1) {
    bf16x8 h;
    h[0] = (__bf16)v0[0]; h[1] = (__bf16)v0[1];
    h[2] = (__bf16)v0[2]; h[3] = (__bf16)v0[3];
    h[4] = (__bf16)v1[0]; h[5] = (__bf16)v1[1];
    h[6] = (__bf16)v1[2]; h[7] = (__bf16)v1[3];
    return __builtin_bit_cast(s16x8, h);
}

// Mask (j<=n) then convert: row n of W, columns jbase..jbase+7.
__device__ __forceinline__ s16x8 cvt8_mask(f32x4 v0, f32x4 v1, int jbase, int n) {
    float t[8] = {v0[0], v0[1], v0[2], v0[3], v1[0], v1[1], v1[2], v1[3]};
    bf16x8 h;
#pragma unroll
    for (int e = 0; e < 8; ++e)
        h[e] = (__bf16)((jbase + e) <= n ? t[e] : 0.0f);
    return __builtin_bit_cast(s16x8, h);
}

// X: (M=262144, 256) row-major fp32; W: (256,256) row-major fp32 (row i = weights over j);
// bias: (256,) fp32; out: (M, 256) row-major fp32.
// Block computes BM(64) x 256 output tile; 4 waves, each 64 rows x 64 cols.
// Occupancy target: 3 blocks/CU (12 waves/CU) — LDS 50 KiB, VGPR <= 170.
__global__ __launch_bounds__(256, 3)
void triu_gemm_kernel(const float* __restrict__ X, const float* __restrict__ W,
                      const float* __restrict__ bias, float* __restrict__ out) {
    __shared__ __align__(16) unsigned short As[2][BM * LDST];    // 2 x  5120 B
    __shared__ __align__(16) unsigned short Bs[2][TDIM * LDST];  // 2 x 20480 B

    const int tid  = threadIdx.x;
    const int wave = tid >> 6;
    const int lane = tid & 63;
    const int quad = lane >> 4;
    const int l16  = lane & 15;
    const int wn   = wave;          // 64-col slice, 0..3

    const long m0 = (long)blockIdx.x * BM;
    const int rr = tid >> 2;        // 0..63 : row within tile
    const int kq = (tid & 3) * 8;   // 0,8,16,24 : k-quadrant

    f32x4 acc[4][4];
#pragma unroll
    for (int i = 0; i < 4; ++i)
#pragma unroll
        for (int j = 0; j < 4; ++j)
            acc[i][j] = (f32x4){0.f, 0.f, 0.f, 0.f};

    f32x4 pa[2];      // X prefetch (one row-slice of 8 floats per thread)
    f32x4 pw[4][2];   // W prefetch (4 row-blocks x 8 floats)

    // Stage-B with compile-time mask pruning: row-block fully at/below the diagonal
    // band (p*64 >= kbase+31) takes the unmasked path; branch folds (p,kbase const).
#define STAGE_B(buf, p, kbase)                                                     \
    *(s16x8*)&Bs[buf][((p) * 64 + rr) * LDST + kq] =                               \
        (((p) * 64) >= (kbase) + 31)                                               \
            ? cvt8(pw[p][0], pw[p][1])                                             \
            : cvt8_mask(pw[p][0], pw[p][1], (kbase) + kq, (p) * 64 + rr)

    // ---------- prologue: stage K-tile 0 into buffer 0 ----------
    {
        const float* src = X + (m0 + rr) * TDIM + kq;
        pa[0] = *(const f32x4*)src;
        pa[1] = *(const f32x4*)(src + 4);
    }
#pragma unroll
    for (int p = 0; p < 4; ++p) {
        const float* src = W + (p * 64 + rr) * TDIM + kq;
        pw[p][0] = *(const f32x4*)src;
        pw[p][1] = *(const f32x4*)(src + 4);
    }
    *(s16x8*)&As[0][rr * LDST + kq] = cvt8(pa[0], pa[1]);
#pragma unroll
    for (int p = 0; p < 4; ++p)
        STAGE_B(0, p, 0);
    __syncthreads();

    // ---------- main loop: double-buffered LDS, 1 barrier per K-step ----------
#pragma unroll
    for (int t = 0; t < NSTEP; ++t) {
        const int k0  = t * BK;
        const int k1  = k0 + BK;
        const int cur = t & 1;

        // Issue next-tile global loads FIRST; the waitcnt lands at the stage
        // phase, so load latency hides under frag-reads + MFMA.
        if (t < NSTEP - 1) {
            const float* src = X + (m0 + rr) * TDIM + (k1 + kq);
            pa[0] = *(const f32x4*)src;
            pa[1] = *(const f32x4*)(src + 4);
#pragma unroll
            for (int p = 0; p < 4; ++p) {
                if (p * 64 + 63 >= k1) {   // row-block entirely masked at k1 -> dead, skip
                    const float* wsrc = W + (p * 64 + rr) * TDIM + (k1 + kq);
                    pw[p][0] = *(const f32x4*)wsrc;
                    pw[p][1] = *(const f32x4*)(wsrc + 4);
                }
            }
        }

        // Triangle skip: wave's 64-col slice is dead once k0 >= (wn+1)*64.
        if (k0 < (wn + 1) * 64) {
            s16x8 af[4];
#pragma unroll
            for (int mi = 0; mi < 4; ++mi)
                af[mi] = *(const s16x8*)&As[cur][(mi * 16 + l16) * LDST + quad * 8];
#pragma unroll
            for (int ni = 0; ni < 4; ++ni) {
                // Fragment rows [f, f+16) all have W==0 when f+15 < k0.
                if (wn * 64 + ni * 16 + 15 >= k0) {
                    const s16x8 bf = *(const s16x8*)&Bs[cur][(wn * 64 + ni * 16 + l16) * LDST + quad * 8];
#pragma unroll
                    for (int mi = 0; mi < 4; ++mi)
                        acc[mi][ni] = __builtin_amdgcn_mfma_f32_16x16x32_bf16(
                            af[mi], bf, acc[mi][ni], 0, 0, 0);
                }
            }
        }

        // Stage tile t+1 into the other buffer; single barrier.
        if (t < NSTEP - 1) {
            *(s16x8*)&As[cur ^ 1][rr * LDST + kq] = cvt8(pa[0], pa[1]);
#pragma unroll
            for (int p = 0; p < 4; ++p)
                if (p * 64 + 63 >= k1)
                    STAGE_B(cur ^ 1, p, k1);
            __syncthreads();
        }
    }
#undef STAGE_B

    // ---------- epilogue: bias add + store. C/D layout: col = lane&15, row = quad*4 + reg ----------
#pragma unroll
    for (int ni = 0; ni < 4; ++ni) {
        const int n = wn * 64 + ni * 16 + l16;
        const float bv = bias[n];
#pragma unroll
        for (int mi = 0; mi < 4; ++mi) {
            const long mb = m0 + mi * 16 + quad * 4;
            float* dst = out + mb * TDIM + n;
#pragma unroll
            for (int r = 0; r < 4; ++r)
                dst[(long)r * TDIM] = acc[mi][ni][r] + bv;
        }
    }
}

extern "C" void kernel_launch(void* const* d_in, const int* in_sizes, int n_in,
                              void* d_out, int out_size, void* d_ws, size_t ws_size,
                              hipStream_t stream) {
    const float* X    = (const float*)d_in[0];   // (256,1024,256) = (M=262144, 256)
    const float* W    = (const float*)d_in[1];   // (256,256)
    const float* bias = (const float*)d_in[2];   // (256,)
    float* out        = (float*)d_out;           // (M, 256)
    (void)d_ws; (void)ws_size;

    const int M = 256 * 1024;                    // B*C
    dim3 grid(M / BM);                           // 4096 blocks
    dim3 block(256);
    triu_gemm_kernel<<<grid, block, 0, stream>>>(X, W, bias, out);
}